// Round 3
// baseline (421.594 us; speedup 1.0000x reference)
//
#include <hip/hip_runtime.h>
#include <math.h>

#define B_   8
#define T_   2048
#define J_   17
#define D_   129
#define d_   128
#define H_   8
#define BJ_  136
#define EPS_ 1e-6f
#define CH   8
#define RPB  (T_ / CH)      // 256
#define NIT  (RPB / 64)     // 4
#define KVSTRIDE 2176       // per-bj floats in kvw: 2048 kv + 128 ksum

typedef short bf8 __attribute__((ext_vector_type(8)));   // 8 bf16 = 4 VGPRs
typedef float fx4 __attribute__((ext_vector_type(4)));
typedef unsigned long long ull;

__device__ __forceinline__ float phi_f(float x) {
    return x > 0.f ? x + 1.f : __expf(x);
}
__device__ __forceinline__ short f2b(float f) {            // fp32->bf16 RNE
    union { float f; unsigned u; } c; c.f = f;
    unsigned u = c.u + 0x7fffu + ((c.u >> 16) & 1u);
    return (short)(u >> 16);
}

// ============================================================================
// Pass A: k/v GEMM + per-head kv, ksum accumulation (atomic into kvw).
// Wave w owns heads 2w,2w+1: k-cols 128+32w..+31 (nt 0,1) and v-cols
// 256+32w..+31 (nt 2,3) -> kT/vT -> kv MFMA is INTRA-WAVE (no barrier).
// Optionally (WX) writes x as bf16 to xbf for pass_out.
// ============================================================================
template<bool WX>
__global__ __launch_bounds__(256, 2) void pass_kv(
        const float* __restrict__ x, const float* __restrict__ wqkv,
        const float* __restrict__ bqkv, float* __restrict__ kvw,
        short* __restrict__ xbf) {
    const int bj = blockIdx.y, b = bj / J_, j = bj % J_;
    const int t0 = blockIdx.x * RPB;
    const int tid = threadIdx.x, wave = tid >> 6, lane = tid & 63;
    const int quad = lane >> 4, l16 = lane & 15;

    __shared__ short sx[64 * 136];
    __shared__ short kT[128 * 72];   // k_m^T : [feat][t_local]
    __shared__ short vT[128 * 72];   // v^T

    // B fragments: nt<2 -> k cols, nt>=2 -> v cols (head-aligned per wave)
    bf8 wf[4][4];
    float bias[4];
    #pragma unroll
    for (int nt = 0; nt < 4; ++nt) {
        const int n = (nt < 2) ? (d_ + wave * 32 + nt * 16 + l16)
                               : (2 * d_ + wave * 32 + (nt - 2) * 16 + l16);
        bias[nt] = bqkv[n];
        #pragma unroll
        for (int ks = 0; ks < 4; ++ks) {
            const float* p = wqkv + (size_t)n * d_ + ks * 32 + quad * 8;
            bf8 t;
            #pragma unroll
            for (int q2 = 0; q2 < 8; ++q2) t[q2] = f2b(p[q2]);
            wf[nt][ks] = t;
        }
    }

    fx4 kva[2];
    kva[0] = (fx4){0.f, 0.f, 0.f, 0.f};
    kva[1] = (fx4){0.f, 0.f, 0.f, 0.f};
    float ksp[2] = {0.f, 0.f};

    for (int it = 0; it < NIT; ++it) {
        __syncthreads();
        const int tb = t0 + it * 64;
        #pragma unroll
        for (int i = 0; i < 8; ++i) {       // stage 64x128 fp32 -> bf16
            const int F = tid + 256 * i, row = F >> 5, c4 = F & 31;
            const float* xr = x + ((size_t)((b * T_ + tb + row) * J_ + j)) * D_ + 1 + 4 * c4;
            ull pk = 0;
            #pragma unroll
            for (int q2 = 0; q2 < 4; ++q2)
                pk |= ((ull)(unsigned short)f2b(xr[q2])) << (16 * q2);
            *reinterpret_cast<ull*>(&sx[row * 136 + 4 * c4]) = pk;
            if (WX)
                *reinterpret_cast<ull*>(&xbf[((size_t)bj * T_ + tb + row) * d_ + 4 * c4]) = pk;
        }
        __syncthreads();

        fx4 acc[4][4];
        #pragma unroll
        for (int nt = 0; nt < 4; ++nt)
            #pragma unroll
            for (int mt = 0; mt < 4; ++mt) acc[nt][mt] = (fx4){0.f, 0.f, 0.f, 0.f};

        #pragma unroll
        for (int ks = 0; ks < 4; ++ks) {
            bf8 af[4];
            #pragma unroll
            for (int mt = 0; mt < 4; ++mt)
                af[mt] = *reinterpret_cast<const bf8*>(
                    &sx[(mt * 16 + l16) * 136 + ks * 32 + quad * 8]);
            #pragma unroll
            for (int nt = 0; nt < 4; ++nt)
                #pragma unroll
                for (int mt = 0; mt < 4; ++mt)
                    acc[nt][mt] = __builtin_amdgcn_mfma_f32_16x16x32_bf16(
                        af[mt], wf[nt][ks], acc[nt][mt], 0, 0, 0);
        }

        // epilogue: bias (+phi for k), transpose-write (intra-wave rows)
        #pragma unroll
        for (int nt = 0; nt < 4; ++nt) {
            const bool isk = (nt < 2);
            short* dst = isk ? kT : vT;
            const int frow = wave * 32 + (nt & 1) * 16 + l16;
            #pragma unroll
            for (int mt = 0; mt < 4; ++mt) {
                ull pk = 0;
                #pragma unroll
                for (int r = 0; r < 4; ++r) {
                    float v2 = acc[nt][mt][r] + bias[nt];
                    if (isk) { v2 = phi_f(v2); ksp[nt & 1] += v2; }
                    pk |= ((ull)(unsigned short)f2b(v2)) << (16 * r);
                }
                *reinterpret_cast<ull*>(&dst[frow * 72 + mt * 16 + quad * 4]) = pk;
            }
        }

        // kv[h] += k_m^T * v, heads owned by this wave -> no barrier needed
        #pragma unroll
        for (int hh = 0; hh < 2; ++hh) {
            const int hrow = wave * 32 + hh * 16 + l16;
            #pragma unroll
            for (int ks2 = 0; ks2 < 2; ++ks2) {
                bf8 ak = *reinterpret_cast<const bf8*>(&kT[hrow * 72 + ks2 * 32 + quad * 8]);
                bf8 bv = *reinterpret_cast<const bf8*>(&vT[hrow * 72 + ks2 * 32 + quad * 8]);
                kva[hh] = __builtin_amdgcn_mfma_f32_16x16x32_bf16(ak, bv, kva[hh], 0, 0, 0);
            }
        }
    }

    // commit: kv stored as [bj][h][e=v-feat][i=k-feat] (i contiguous)
    #pragma unroll
    for (int hh = 0; hh < 2; ++hh) {
        const int h = wave * 2 + hh;
        float* p = kvw + (size_t)bj * KVSTRIDE + h * 256 + l16 * 16 + quad * 4;
        #pragma unroll
        for (int r = 0; r < 4; ++r) atomicAdd(p + r, kva[hh][r]);
    }
    #pragma unroll
    for (int nt = 0; nt < 2; ++nt) {
        float s = ksp[nt];
        s += __shfl_xor(s, 16);
        s += __shfl_xor(s, 32);
        if (lane < 16)
            atomicAdd(kvw + (size_t)bj * KVSTRIDE + 2048 + wave * 32 + nt * 16 + l16, s);
    }
}

// ============================================================================
// Pass B: q GEMM -> phi -> 1/denom (register butterfly, folded into qm)
// -> agg MFMA (intra-wave, writes back into qm region) -> out GEMM -> store.
// 4 barriers/tile, LDS ~42KB -> 3 blocks/CU.
// ============================================================================
template<bool UX>
__global__ __launch_bounds__(256, 2) void pass_out(
        const float* __restrict__ x, const float* __restrict__ wqkv,
        const float* __restrict__ bqkv, const float* __restrict__ wout,
        const float* __restrict__ bout, const float* __restrict__ kvw,
        const short* __restrict__ xbf, float* __restrict__ out) {
    const int bj = blockIdx.y, b = bj / J_, j = bj % J_;
    const int t0 = blockIdx.x * RPB;
    const int tid = threadIdx.x, wave = tid >> 6, lane = tid & 63;
    const int quad = lane >> 4, l16 = lane & 15;

    __shared__ short sx[64 * 136];
    __shared__ short qm[64 * 136];          // q_m (scaled); later reused as agg
    __shared__ short kvT[H_ * 16 * 24];     // [h][e][i], i contiguous
    __shared__ float kss[d_];
    __shared__ float rnorm[64];
    short* sag = qm;                        // agg overwrites qm (intra-wave safe)

    bf8 wqf[2][4], wof[2][4];
    float bq2[2], bo2[2];
    #pragma unroll
    for (int nt = 0; nt < 2; ++nt) {
        const int n = wave * 32 + nt * 16 + l16;
        bq2[nt] = bqkv[n];
        bo2[nt] = bout[n];
        #pragma unroll
        for (int ks = 0; ks < 4; ++ks) {
            const float* p  = wqkv + (size_t)n * d_ + ks * 32 + quad * 8;
            const float* p2 = wout + (size_t)n * d_ + ks * 32 + quad * 8;
            bf8 t, t2;
            #pragma unroll
            for (int q2 = 0; q2 < 8; ++q2) { t[q2] = f2b(p[q2]); t2[q2] = f2b(p2[q2]); }
            wqf[nt][ks] = t;
            wof[nt][ks] = t2;
        }
    }

    // stage final kv -> kvT (bf16) and ksum -> kss (fp32)
    for (int s4 = tid; s4 < 544; s4 += 256) {
        const float4 v4 = *reinterpret_cast<const float4*>(
            kvw + (size_t)bj * KVSTRIDE + 4 * s4);
        if (s4 < 512) {
            const int row = s4 >> 2, i0 = (s4 & 3) * 4;
            ull pk = ((ull)(unsigned short)f2b(v4.x)) |
                     ((ull)(unsigned short)f2b(v4.y) << 16) |
                     ((ull)(unsigned short)f2b(v4.z) << 32) |
                     ((ull)(unsigned short)f2b(v4.w) << 48);
            *reinterpret_cast<ull*>(&kvT[row * 24 + i0]) = pk;
        } else {
            *reinterpret_cast<float4*>(&kss[4 * s4 - 2048]) = v4;
        }
    }
    __syncthreads();
    float ksr[2];
    #pragma unroll
    for (int nt = 0; nt < 2; ++nt) ksr[nt] = kss[wave * 32 + nt * 16 + l16];

    for (int it = 0; it < NIT; ++it) {
        const int tb = t0 + it * 64;
        if (UX) {
            #pragma unroll
            for (int i = 0; i < 4; ++i) {
                const int F = tid + 256 * i, row = F >> 4, c8 = F & 15;
                const bf8 v = *reinterpret_cast<const bf8*>(
                    &xbf[((size_t)bj * T_ + tb + row) * d_ + 8 * c8]);
                *reinterpret_cast<bf8*>(&sx[row * 136 + 8 * c8]) = v;
            }
        } else {
            #pragma unroll
            for (int i = 0; i < 8; ++i) {
                const int F = tid + 256 * i, row = F >> 5, c4 = F & 31;
                const float* xr = x + ((size_t)((b * T_ + tb + row) * J_ + j)) * D_ + 1 + 4 * c4;
                ull pk = 0;
                #pragma unroll
                for (int q2 = 0; q2 < 4; ++q2)
                    pk |= ((ull)(unsigned short)f2b(xr[q2])) << (16 * q2);
                *reinterpret_cast<ull*>(&sx[row * 136 + 4 * c4]) = pk;
            }
        }
        if (tid < 64) rnorm[tid] = 0.f;
        __syncthreads();

        // q GEMM
        fx4 acc[2][4];
        #pragma unroll
        for (int nt = 0; nt < 2; ++nt)
            #pragma unroll
            for (int mt = 0; mt < 4; ++mt) acc[nt][mt] = (fx4){0.f, 0.f, 0.f, 0.f};
        #pragma unroll
        for (int ks = 0; ks < 4; ++ks) {
            bf8 af[4];
            #pragma unroll
            for (int mt = 0; mt < 4; ++mt)
                af[mt] = *reinterpret_cast<const bf8*>(
                    &sx[(mt * 16 + l16) * 136 + ks * 32 + quad * 8]);
            #pragma unroll
            for (int nt = 0; nt < 2; ++nt)
                #pragma unroll
                for (int mt = 0; mt < 4; ++mt)
                    acc[nt][mt] = __builtin_amdgcn_mfma_f32_16x16x32_bf16(
                        af[mt], wqf[nt][ks], acc[nt][mt], 0, 0, 0);
        }

        // phi + denominator butterfly (over l16 group = i of head h) + scaled
        // qm write. dens lane mapping (row from quad/r, h from nt) matches agg.
        #pragma unroll
        for (int nt = 0; nt < 2; ++nt) {
            const int col = wave * 32 + nt * 16 + l16;
            #pragma unroll
            for (int mt = 0; mt < 4; ++mt)
                #pragma unroll
                for (int r = 0; r < 4; ++r) {
                    const float qv = phi_f(acc[nt][mt][r] + bq2[nt]);
                    float p = qv * ksr[nt];
                    p += __shfl_xor(p, 1);
                    p += __shfl_xor(p, 2);
                    p += __shfl_xor(p, 4);
                    p += __shfl_xor(p, 8);
                    const float dinv = 1.f / fmaxf(p, EPS_);
                    qm[(mt * 16 + quad * 4 + r) * 136 + col] = f2b(qv * dinv);
                }
        }

        // agg = q_m_scaled @ kv[h] — intra-wave (own heads/cols), no barrier.
        // K=16 padded to 32 with zeros. Writes overwrite qm (reads precede
        // writes per mt; disjoint rows/cols otherwise; DS pipe is in-order).
        #pragma unroll
        for (int hh = 0; hh < 2; ++hh) {
            const int h = wave * 2 + hh;
            bf8 bk = (bf8){0, 0, 0, 0, 0, 0, 0, 0};
            if (quad < 2)
                bk = *reinterpret_cast<const bf8*>(&kvT[(h * 16 + l16) * 24 + quad * 8]);
            #pragma unroll
            for (int mt = 0; mt < 4; ++mt) {
                bf8 aq = (bf8){0, 0, 0, 0, 0, 0, 0, 0};
                if (quad < 2)
                    aq = *reinterpret_cast<const bf8*>(
                        &qm[(mt * 16 + l16) * 136 + h * 16 + quad * 8]);
                fx4 ag = __builtin_amdgcn_mfma_f32_16x16x32_bf16(
                    aq, bk, (fx4){0.f, 0.f, 0.f, 0.f}, 0, 0, 0);
                #pragma unroll
                for (int r = 0; r < 4; ++r)
                    sag[(mt * 16 + quad * 4 + r) * 136 + h * 16 + l16] = f2b(ag[r]);
            }
        }
        __syncthreads();

        // out GEMM
        fx4 ya[2][4];
        #pragma unroll
        for (int nt = 0; nt < 2; ++nt)
            #pragma unroll
            for (int mt = 0; mt < 4; ++mt) ya[nt][mt] = (fx4){0.f, 0.f, 0.f, 0.f};
        #pragma unroll
        for (int ks = 0; ks < 4; ++ks) {
            bf8 af[4];
            #pragma unroll
            for (int mt = 0; mt < 4; ++mt)
                af[mt] = *reinterpret_cast<const bf8*>(
                    &sag[(mt * 16 + l16) * 136 + ks * 32 + quad * 8]);
            #pragma unroll
            for (int nt = 0; nt < 2; ++nt)
                #pragma unroll
                for (int mt = 0; mt < 4; ++mt)
                    ya[nt][mt] = __builtin_amdgcn_mfma_f32_16x16x32_bf16(
                        af[mt], wof[nt][ks], ya[nt][mt], 0, 0, 0);
        }

        // stores + row-norm
        #pragma unroll
        for (int mt = 0; mt < 4; ++mt) {
            float sq[4] = {0.f, 0.f, 0.f, 0.f};
            #pragma unroll
            for (int nt = 0; nt < 2; ++nt) {
                const int col = wave * 32 + nt * 16 + l16;
                #pragma unroll
                for (int r = 0; r < 4; ++r) {
                    const float y = ya[nt][mt][r] + bo2[nt];
                    const int t = tb + mt * 16 + quad * 4 + r;
                    out[((size_t)(b * T_ + t) * J_ + j) * D_ + 1 + col] = y;
                    sq[r] += y * y;
                }
            }
            #pragma unroll
            for (int r = 0; r < 4; ++r) {
                float s = sq[r];
                s += __shfl_xor(s, 1);
                s += __shfl_xor(s, 2);
                s += __shfl_xor(s, 4);
                s += __shfl_xor(s, 8);
                if (l16 == 0) atomicAdd(&rnorm[mt * 16 + quad * 4 + r], s);
            }
        }
        __syncthreads();
        if (tid < 64)
            out[((size_t)(b * T_ + tb + tid) * J_ + j) * D_] = sqrtf(1.f + rnorm[tid]);
        __syncthreads();
    }
}

extern "C" void kernel_launch(void* const* d_in, const int* in_sizes, int n_in,
                              void* d_out, int out_size, void* d_ws, size_t ws_size,
                              hipStream_t stream) {
    const float* x    = (const float*)d_in[0];
    const float* wqkv = (const float*)d_in[1];
    const float* bqkv = (const float*)d_in[2];
    const float* wout = (const float*)d_in[3];
    const float* bout = (const float*)d_in[4];
    float* out = (float*)d_out;

    float* kvw = (float*)d_ws;
    const size_t kv_bytes  = (size_t)BJ_ * KVSTRIDE * sizeof(float);   // 1,183,744
    const size_t xbf_bytes = (size_t)BJ_ * T_ * d_ * sizeof(short);    // 71,303,168
    short* xbf = (short*)((char*)d_ws + kv_bytes);
    const bool use_xbf = (ws_size >= kv_bytes + xbf_bytes);            // constant per problem

    hipMemsetAsync(d_ws, 0, kv_bytes, stream);

    dim3 blk(256);
    dim3 grd(CH, BJ_);
    if (use_xbf) {
        pass_kv<true><<<grd, blk, 0, stream>>>(x, wqkv, bqkv, kvw, xbf);
        pass_out<true><<<grd, blk, 0, stream>>>(x, wqkv, bqkv, wout, bout, kvw, xbf, out);
    } else {
        pass_kv<false><<<grd, blk, 0, stream>>>(x, wqkv, bqkv, kvw, xbf);
        pass_out<false><<<grd, blk, 0, stream>>>(x, wqkv, bqkv, wout, bout, kvw, xbf, out);
    }
}